// Round 4
// baseline (164.417 us; speedup 1.0000x reference)
//
#include <hip/hip_runtime.h>
#include <hip/hip_bf16.h>

// out[b,h,w,dy*9+dx] = leaky_relu( mean_c( prv[b,h,w,c] * nxt[b,h+dy-4,w+dx-4,c] ), 0.1 )
// Banded bf16 MFMA. dy split across blocks (3 dy per block) to cut accumulator
// registers 144->48 and reach 16 waves/CU (4 independent 4-wave blocks) for MLP.

#define B_ 8
#define H_ 128
#define W_ 128
#define C_ 192
#define ND 9
#define NDISP 81
#define HT 4            // output rows per block (one per wave)
#define WT 32           // output cols per block
#define NDY 3           // dy values per block
#define KS 32           // channels per k-step
#define NK 6            // 192/32
#define BROWS (HT + NDY - 1)   // 6 nxt rows staged
#define BCOLS (WT + 8)         // 40 nxt cols staged
#define ACH (4 * HT * WT)          // 512 16B A-chunks per kstep
#define BCH (4 * BROWS * BCOLS)    // 960 16B B-chunks per kstep
#define TCH (ACH + BCH)            // 1472

typedef short short8 __attribute__((ext_vector_type(8)));
typedef float f32x4 __attribute__((ext_vector_type(4)));

static __device__ __forceinline__ short bf1(float f) {
    __hip_bfloat16 h = __float2bfloat16(f);       // compiler can fuse pairs to v_cvt_pk_bf16_f32
    return __builtin_bit_cast(short, h);
}

static __device__ __forceinline__ short8 cvt8(float4 x, float4 y) {
    short8 v;
    v[0] = bf1(x.x); v[1] = bf1(x.y); v[2] = bf1(x.z); v[3] = bf1(x.w);
    v[4] = bf1(y.x); v[5] = bf1(y.y); v[6] = bf1(y.z); v[7] = bf1(y.w);
    return v;
}

__global__ __launch_bounds__(256, 4)
void cv_mfma(const float* __restrict__ prv, const float* __restrict__ nxt,
             float* __restrict__ out) {
    // LDS: [c-chunk][pixel][8 bf16]; wave frag reads are contiguous 256B runs -> conflict-free.
    __shared__ short8 sm[TCH];   // 23 KB: sA = sm[0..ACH), sB = sm[ACH..)

    const int tid = threadIdx.x;
    const int w0 = blockIdx.x * WT;
    const int h0 = blockIdx.y * HT;
    const int z  = blockIdx.z;          // bb*3 + g  (siblings 128 blocks apart -> same XCD)
    const int bb = z / 3;
    const int g  = z - bb * 3;
    const int dy0 = 3 * g;

    const int lane = tid & 63;
    const int wid  = tid >> 6;          // 0..3: this wave's output row (h0+wid)
    const int lq = lane & 15;
    const int lc = lane >> 4;

    const int hB = h0 + dy0 - 4;        // global h of staged B row 0

    f32x4 acc[NDY][4];
#pragma unroll
    for (int j = 0; j < NDY; ++j)
#pragma unroll
        for (int t = 0; t < 4; ++t)
            acc[j][t] = (f32x4){0.f, 0.f, 0.f, 0.f};

    for (int ks = 0; ks < NK; ++ks) {
        if (ks) __syncthreads();
        const int cb = ks * KS;

        // ---- stage A (prv tile) + B (nxt rows hB..hB+5, cols w0-4..w0+35), f32 -> bf16
        for (int idx = tid; idx < TCH; idx += 256) {
            float4 x = make_float4(0.f, 0.f, 0.f, 0.f);
            float4 y = x;
            if (idx < ACH) {
                const int c = idx >> 7;          // /(HT*WT)
                const int rem = idx & 127;
                const int r = rem >> 5;
                const int p = rem & 31;
                const float* gp = prv + ((size_t)((bb * H_ + h0 + r) * W_ + w0 + p)) * C_ + cb + c * 8;
                x = *(const float4*)gp;
                y = *(const float4*)(gp + 4);
            } else {
                const int t = idx - ACH;
                const int c = t / (BROWS * BCOLS);
                const int rem = t - c * (BROWS * BCOLS);
                const int r = rem / BCOLS;
                const int p = rem - r * BCOLS;
                const int gh = hB + r;
                const int gw = w0 - 4 + p;
                if ((unsigned)gh < (unsigned)H_ && (unsigned)gw < (unsigned)W_) {
                    const float* gp = nxt + ((size_t)((bb * H_ + gh) * W_ + gw)) * C_ + cb + c * 8;
                    x = *(const float4*)gp;
                    y = *(const float4*)(gp + 4);
                }
            }
            sm[idx] = cvt8(x, y);
        }
        __syncthreads();

        // ---- compute: wave wid = row h0+wid; 3 dy; 2 w-tiles x 2 col-tiles each
        const short8 a0 = sm[lc * (HT * WT) + wid * WT + lq];
        const short8 a1 = sm[lc * (HT * WT) + wid * WT + 16 + lq];
#pragma unroll
        for (int j = 0; j < NDY; ++j) {
            const int base = ACH + lc * (BROWS * BCOLS) + (wid + j) * BCOLS + lq;
            const short8 b0 = sm[base];        // cols w0-4+q
            const short8 b1 = sm[base + 16];   // cols w0+12+q
            const short8 b2 = sm[base + 32];   // cols w0+28+q
            acc[j][0] = __builtin_amdgcn_mfma_f32_16x16x32_bf16(a0, b0, acc[j][0], 0, 0, 0);
            acc[j][1] = __builtin_amdgcn_mfma_f32_16x16x32_bf16(a0, b1, acc[j][1], 0, 0, 0);
            acc[j][2] = __builtin_amdgcn_mfma_f32_16x16x32_bf16(a1, b1, acc[j][2], 0, 0, 0);
            acc[j][3] = __builtin_amdgcn_mfma_f32_16x16x32_bf16(a1, b2, acc[j][3], 0, 0, 0);
        }
    }

    // ---- epilogue: D layout col=lane&15, row=4*(lane>>4)+reg (verified m89/m91)
    // dx = q - r (col-tile at -4 rel. to w-tile) or q - r + 16 (col-tile at +12); exclusive.
    const float inv = 1.0f / (float)C_;
    const int h = h0 + wid;
#pragma unroll
    for (int wt = 0; wt < 2; ++wt) {
#pragma unroll
        for (int rg = 0; rg < 4; ++rg) {
            const int r = 4 * lc + rg;
            const int w = w0 + 16 * wt + r;
            float* o = out + ((size_t)((bb * H_ + h) * W_ + w)) * NDISP;
            const int dxa = lq - r;
            const int dxb = dxa + 16;
            if (dxa >= 0 && dxa <= 8) {
#pragma unroll
                for (int j = 0; j < NDY; ++j) {
                    const float v = acc[j][2 * wt][rg] * inv;
                    o[(dy0 + j) * ND + dxa] = v >= 0.f ? v : 0.1f * v;
                }
            }
            if (dxb <= 8) {
#pragma unroll
                for (int j = 0; j < NDY; ++j) {
                    const float v = acc[j][2 * wt + 1][rg] * inv;
                    o[(dy0 + j) * ND + dxb] = v >= 0.f ? v : 0.1f * v;
                }
            }
        }
    }
}

extern "C" void kernel_launch(void* const* d_in, const int* in_sizes, int n_in,
                              void* d_out, int out_size, void* d_ws, size_t ws_size,
                              hipStream_t stream) {
    const float* prv = (const float*)d_in[0];
    const float* nxt = (const float*)d_in[1];
    float* out = (float*)d_out;

    dim3 grid(W_ / WT, H_ / HT, B_ * 3);   // (4, 32, 24) = 3072 blocks
    cv_mfma<<<grid, 256, 0, stream>>>(prv, nxt, out);
}

// Round 5
// 98.567 us; speedup vs baseline: 1.6681x; 1.6681x over previous
//
#include <hip/hip_runtime.h>
#include <hip/hip_bf16.h>

// out[b,h,w,dy*9+dx] = leaky_relu( mean_c( prv[b,h,w,c] * nxt[b,h+dy-4,w+dx-4,c] ), 0.1 )
// Banded bf16 MFMA. Block = 4 waves = 4h x 16w tile, FULL dy=9 (no dy-split redundancy).
// Per (h,dy): two overlapping 16x16x32 MFMAs with B col-tiles at staged-col offsets 0 and 8:
//   tile0 covers output rows r<8 (dx = q-r), tile1 covers rows r>=8 (dx = q-r+8).
// acc = 9*2 f32x4 = 72 regs -> 4 waves/SIMD (4 independent blocks/CU).
// Staging: 6 hoisted (ptr,ok) slots per thread, loads issued in 2 unrolled triples
// (batched ILP — the R4 regression was a rolled, serialized staging loop).

#define B_ 8
#define H_ 128
#define W_ 128
#define C_ 192
#define ND 9
#define NDISP 81
#define HT 4            // output rows per block (one per wave)
#define WT 16           // output cols per block
#define KS 32           // channels per k-step
#define NK 6            // 192/32
#define BROWS 12        // HT + ND - 1 nxt rows staged
#define BCOLS 24        // WT + 8 nxt cols staged
#define APX (HT * WT)          // 64 prv pixels
#define BPX (BROWS * BCOLS)    // 288 nxt pixels
#define ACH (4 * APX)          // 256 16B A-chunks per kstep
#define BCH (4 * BPX)          // 1152 16B B-chunks per kstep
#define TCH (ACH + BCH)        // 1408
#define NSLOT 6                // ceil(TCH/256)

typedef short short8 __attribute__((ext_vector_type(8)));
typedef float f32x4 __attribute__((ext_vector_type(4)));

static __device__ __forceinline__ short bf1(float f) {
    __hip_bfloat16 h = __float2bfloat16(f);   // pairs fuse to v_cvt_pk_bf16_f32
    return __builtin_bit_cast(short, h);
}

static __device__ __forceinline__ short8 cvt8(float4 x, float4 y) {
    short8 v;
    v[0] = bf1(x.x); v[1] = bf1(x.y); v[2] = bf1(x.z); v[3] = bf1(x.w);
    v[4] = bf1(y.x); v[5] = bf1(y.y); v[6] = bf1(y.z); v[7] = bf1(y.w);
    return v;
}

__global__ __launch_bounds__(256, 4)
void cv_mfma(const float* __restrict__ prv, const float* __restrict__ nxt,
             float* __restrict__ out) {
    // LDS: [c-chunk][pixel][8 bf16]; every 16-lane frag read = 256B contiguous run
    // (the R2-verified conflict-free pattern). 1408 * 16B = 22.5 KB.
    __shared__ short8 sm[TCH];

    const int tid = threadIdx.x;
    const int w0 = blockIdx.x * WT;
    const int h0 = blockIdx.y * HT;
    const int b  = blockIdx.z;

    const int lane = tid & 63;
    const int wid  = tid >> 6;      // 0..3: wave handles output row h0+wid
    const int lq = lane & 15;
    const int lc = lane >> 4;

    // ---- hoisted staging slots (k-step adds a constant 128B offset)
    const float* gp[NSLOT];
    bool ok[NSLOT];
#pragma unroll
    for (int i = 0; i < NSLOT; ++i) {
        const int idx = tid + i * 256;
        ok[i] = false;
        gp[i] = prv;                 // dummy, never dereferenced when !ok
        if (idx < TCH) {
            if (idx < ACH) {         // A: prv[h0+r][w0+p], always in range
                const int c = idx >> 6;
                const int px = idx & (APX - 1);
                const int r = px >> 4;
                const int p = px & 15;
                gp[i] = prv + (size_t)(((b * H_ + h0 + r) * W_ + w0 + p)) * C_ + c * 8;
                ok[i] = true;
            } else {                 // B: nxt[h0-4+row][w0-4+col]
                const int t = idx - ACH;
                const int c = t / BPX;
                const int rem = t - c * BPX;
                const int row = rem / BCOLS;
                const int col = rem - row * BCOLS;
                const int gh = h0 - 4 + row;
                const int gw = w0 - 4 + col;
                ok[i] = ((unsigned)gh < (unsigned)H_) && ((unsigned)gw < (unsigned)W_);
                gp[i] = nxt + (long long)((b * H_ + gh) * W_ + gw) * C_ + c * 8;
            }
        }
    }

    f32x4 acc[ND][2];
#pragma unroll
    for (int d = 0; d < ND; ++d) {
        acc[d][0] = (f32x4){0.f, 0.f, 0.f, 0.f};
        acc[d][1] = (f32x4){0.f, 0.f, 0.f, 0.f};
    }

    for (int ks = 0; ks < NK; ++ks) {
        if (ks) __syncthreads();
        const int off = ks * KS;

        // ---- stage: two unrolled triples, loads batched back-to-back
#pragma unroll
        for (int tr = 0; tr < 2; ++tr) {
            float4 x[3], y[3];
#pragma unroll
            for (int j = 0; j < 3; ++j) {
                x[j] = make_float4(0.f, 0.f, 0.f, 0.f);
                y[j] = x[j];
                const int i = 3 * tr + j;
                if (ok[i]) {
                    const float* p = gp[i] + off;
                    x[j] = *(const float4*)p;
                    y[j] = *(const float4*)(p + 4);
                }
            }
#pragma unroll
            for (int j = 0; j < 3; ++j) {
                const int i = 3 * tr + j;
                const int idx = tid + i * 256;
                if (i < NSLOT - 1) {
                    sm[idx] = cvt8(x[j], y[j]);
                } else if (idx < TCH) {       // last slot: wave-uniform guard (tid<128)
                    sm[idx] = cvt8(x[j], y[j]);
                }
            }
        }
        __syncthreads();

        // ---- compute: 9 dy x 2 overlapping col-tiles
        const short8 a0 = sm[lc * APX + wid * WT + lq];
#pragma unroll
        for (int dy = 0; dy < ND; ++dy) {
            const int base = ACH + lc * BPX + (wid + dy) * BCOLS + lq;
            const short8 b0 = sm[base];       // cols w0-4+q
            const short8 b1 = sm[base + 8];   // cols w0+4+q
            acc[dy][0] = __builtin_amdgcn_mfma_f32_16x16x32_bf16(a0, b0, acc[dy][0], 0, 0, 0);
            acc[dy][1] = __builtin_amdgcn_mfma_f32_16x16x32_bf16(a0, b1, acc[dy][1], 0, 0, 0);
        }
    }

    // ---- epilogue: D layout col=lane&15, row=4*(lane>>4)+reg (verified m89/m91)
    // rows r<8 valid in tile0 (dx=q-r), rows r>=8 in tile1 (dx=q-r+8). Static acc index
    // per branch (rule #20: no runtime indexing into ext_vector arrays).
    const float inv = 1.0f / (float)C_;
    const int h = h0 + wid;
    if (lc < 2) {
#pragma unroll
        for (int rg = 0; rg < 4; ++rg) {
            const int r = 4 * lc + rg;
            const int dx = lq - r;
            if (dx >= 0 && dx <= 8) {
                float* o = out + (size_t)((b * H_ + h) * W_ + w0 + r) * NDISP + dx;
#pragma unroll
                for (int dy = 0; dy < ND; ++dy) {
                    const float v = acc[dy][0][rg] * inv;
                    o[dy * ND] = v >= 0.f ? v : 0.1f * v;
                }
            }
        }
    } else {
#pragma unroll
        for (int rg = 0; rg < 4; ++rg) {
            const int r = 4 * lc + rg;
            const int dx = lq - r + 8;
            if (dx >= 0 && dx <= 8) {
                float* o = out + (size_t)((b * H_ + h) * W_ + w0 + r) * NDISP + dx;
#pragma unroll
                for (int dy = 0; dy < ND; ++dy) {
                    const float v = acc[dy][1][rg] * inv;
                    o[dy * ND] = v >= 0.f ? v : 0.1f * v;
                }
            }
        }
    }
}

extern "C" void kernel_launch(void* const* d_in, const int* in_sizes, int n_in,
                              void* d_out, int out_size, void* d_ws, size_t ws_size,
                              hipStream_t stream) {
    const float* prv = (const float*)d_in[0];
    const float* nxt = (const float*)d_in[1];
    float* out = (float*)d_out;

    dim3 grid(W_ / WT, H_ / HT, B_);   // (8, 32, 8) = 2048 blocks
    cv_mfma<<<grid, 256, 0, stream>>>(prv, nxt, out);
}